// Round 4
// baseline (249.645 us; speedup 1.0000x reference)
//
#include <hip/hip_runtime.h>

typedef __bf16 bf16x8 __attribute__((ext_vector_type(8)));
typedef float f32x4 __attribute__((ext_vector_type(4)));
typedef unsigned short u16;
typedef unsigned int u32;

#define BB 4
#define NNCTX 2048
#define CCH 384
#define NHEAD 6
#define DHEAD 64
#define HIDDIM 1536

__device__ __forceinline__ u16 f2bf(float f){
  u32 u = __builtin_bit_cast(u32, f);
  u = u + 0x7fffu + ((u >> 16) & 1u);
  return (u16)(u >> 16);
}
__device__ __forceinline__ float bf2f(u16 h){
  u32 u = ((u32)h) << 16;
  return __builtin_bit_cast(float, u);
}

union U8 { uint4 u; u16 s[8]; bf16x8 v; };

// Merged weight cast: 1769472 elems = 442368 float4 units = 1728 blocks exactly.
__global__ __launch_bounds__(256) void cast_all(const float* __restrict__ w0, const float* __restrict__ w1,
    const float* __restrict__ w2, const float* __restrict__ w3,
    u16* __restrict__ o0, u16* __restrict__ o1, u16* __restrict__ o2, u16* __restrict__ o3){
  int i = blockIdx.x * 256 + threadIdx.x;
  const int n0 = 442368/4, n1 = 147456/4, n2 = 589824/4;
  const float* src; u16* dst; int j;
  if (i < n0){ src = w0; dst = o0; j = i; }
  else if (i < n0 + n1){ src = w1; dst = o1; j = i - n0; }
  else if (i < n0 + n1 + n2){ src = w2; dst = o2; j = i - n0 - n1; }
  else { src = w3; dst = o3; j = i - n0 - n1 - n2; }
  float4 v = ((const float4*)src)[j];
  ushort4 o; o.x = f2bf(v.x); o.y = f2bf(v.y); o.z = f2bf(v.z); o.w = f2bf(v.w);
  ((ushort4*)dst)[j] = o;
}

// One block per row (C=384), 128 threads: each handles 3 elements.
__global__ __launch_bounds__(128) void ln_kernel(const float* __restrict__ x, const float* __restrict__ g,
                                                 const float* __restrict__ bb, u16* __restrict__ out){
  int row = blockIdx.x, t = threadIdx.x;
  const float* xr = x + (size_t)row * CCH;
  float v0 = xr[t], v1 = xr[t + 128], v2 = xr[t + 256];
  float s = v0 + v1 + v2;
  float q = v0 * v0 + v1 * v1 + v2 * v2;
  #pragma unroll
  for (int o = 32; o; o >>= 1){ s += __shfl_down(s, o); q += __shfl_down(q, o); }
  __shared__ float sh[4];
  if ((t & 63) == 0){ int w = t >> 6; sh[w * 2] = s; sh[w * 2 + 1] = q; }
  __syncthreads();
  float sum = sh[0] + sh[2], ssq = sh[1] + sh[3];
  float mu = sum * (1.0f / 384.0f);
  float rstd = rsqrtf(ssq * (1.0f / 384.0f) - mu * mu + 1e-5f);
  size_t base = (size_t)row * CCH;
  out[base + t]       = f2bf((v0 - mu) * rstd * g[t]       + bb[t]);
  out[base + t + 128] = f2bf((v1 - mu) * rstd * g[t + 128] + bb[t + 128]);
  out[base + t + 256] = f2bf((v2 - mu) * rstd * g[t + 256] + bb[t + 256]);
}

// Tiled bf16 MFMA GEMM: C[M,Nn] = A[M,K] @ B[K,Nn]. 64x64 tile, 256 threads (4 waves, 2x2 of 32x32).
// EPI 0: store bf16. EPI 1: fp32 out = resid + acc + bias. EPI 2: bf16 out = gelu(acc + bias).
// DBUF 1: double-buffered LDS + reg prefetch, 1 barrier/iter (for grid-limited launches).
template<int EPI, int DBUF>
__global__ __launch_bounds__(256) void gemm_bf16(const u16* __restrict__ A, const u16* __restrict__ Bm,
    int K, int Nn, u16* __restrict__ outb, const float* __restrict__ bias,
    const float* __restrict__ resid, float* __restrict__ outf)
{
  __shared__ u16 As[DBUF + 1][64][68];
  __shared__ u16 Bs[DBUF + 1][64][68];
  int t = threadIdx.x;
  int bm = blockIdx.y * 64, bn = blockIdx.x * 64;
  int l = t & 63, w = t >> 6;
  int wm = (w >> 1) * 32, wn = (w & 1) * 32;
  f32x4 acc[2][2] = {};
  int ar0 = t >> 3, ac0 = (t & 7) * 8;
  uint4 la0, la1, lb0, lb1;
  auto LOADG = [&](int k0){
    la0 = *(const uint4*)&A[(size_t)(bm + ar0) * K + k0 + ac0];
    la1 = *(const uint4*)&A[(size_t)(bm + ar0 + 32) * K + k0 + ac0];
    lb0 = *(const uint4*)&Bm[(size_t)(k0 + ar0) * Nn + bn + ac0];
    lb1 = *(const uint4*)&Bm[(size_t)(k0 + ar0 + 32) * Nn + bn + ac0];
  };
  auto WRITEL = [&](int bf){
    *(uint4*)&As[bf][ar0][ac0]      = la0;
    *(uint4*)&As[bf][ar0 + 32][ac0] = la1;
    const u16* p0 = (const u16*)&lb0;
    const u16* p1 = (const u16*)&lb1;
    #pragma unroll
    for (int j = 0; j < 8; j++){ Bs[bf][ac0 + j][ar0] = p0[j]; Bs[bf][ac0 + j][ar0 + 32] = p1[j]; }
  };
  auto COMPUTE = [&](int bf){
    #pragma unroll
    for (int ks = 0; ks < 2; ks++){
      int kb = ks * 32 + (l >> 4) * 8;
      bf16x8 a0  = *(const bf16x8*)&As[bf][wm + (l & 15)][kb];
      bf16x8 a1  = *(const bf16x8*)&As[bf][wm + 16 + (l & 15)][kb];
      bf16x8 bb0 = *(const bf16x8*)&Bs[bf][wn + (l & 15)][kb];
      bf16x8 bb1 = *(const bf16x8*)&Bs[bf][wn + 16 + (l & 15)][kb];
      acc[0][0] = __builtin_amdgcn_mfma_f32_16x16x32_bf16(a0, bb0, acc[0][0], 0, 0, 0);
      acc[0][1] = __builtin_amdgcn_mfma_f32_16x16x32_bf16(a0, bb1, acc[0][1], 0, 0, 0);
      acc[1][0] = __builtin_amdgcn_mfma_f32_16x16x32_bf16(a1, bb0, acc[1][0], 0, 0, 0);
      acc[1][1] = __builtin_amdgcn_mfma_f32_16x16x32_bf16(a1, bb1, acc[1][1], 0, 0, 0);
    }
  };
  if constexpr (DBUF){
    int nk = K >> 6;
    LOADG(0);
    WRITEL(0);
    __syncthreads();
    for (int ki = 0; ki < nk; ki++){
      int cur = ki & 1;
      if (ki + 1 < nk) LOADG((ki + 1) << 6);
      COMPUTE(cur);
      if (ki + 1 < nk) WRITEL(cur ^ 1);
      __syncthreads();
    }
  } else {
    for (int k0 = 0; k0 < K; k0 += 64){
      __syncthreads();
      LOADG(k0);
      WRITEL(0);
      __syncthreads();
      COMPUTE(0);
    }
  }
  #pragma unroll
  for (int mi = 0; mi < 2; mi++)
  #pragma unroll
  for (int ni = 0; ni < 2; ni++)
  #pragma unroll
  for (int r = 0; r < 4; r++){
    int row = bm + wm + mi * 16 + ((l >> 4) << 2) + r;
    int col = bn + wn + ni * 16 + (l & 15);
    size_t idx = (size_t)row * Nn + col;
    float v = acc[mi][ni][r];
    if (EPI == 0){
      outb[idx] = f2bf(v);
    } else if (EPI == 1){
      outf[idx] = resid[idx] + v + bias[col];
    } else {
      v += bias[col];
      v = 0.5f * v * (1.0f + erff(v * 0.70710678118f));
      outb[idx] = f2bf(v);
    }
  }
}

// MFMA flash attention, KV-split over blockIdx.z (2 splits x 16 tiles).
// Single-buffered KV LDS (25.5 KB -> 6 blocks/CU) + register prefetch (T14).
// l computed by ones-MFMA (no shfl-sum); defer-max THR=8 skips max-reduce+rescale
// in steady state (P bounded by 2^8, fp32 accum has headroom).
// Outputs UNNORMALIZED O (bf16) + per-row (m,l) for the combine pass.
__global__ __launch_bounds__(256, 6) void attn_mfma(const u16* __restrict__ qkv,
    u16* __restrict__ o0buf, u16* __restrict__ o1buf, float2* __restrict__ mlbuf){
  __shared__ u16 Ks[64][68];        // [key][d]
  __shared__ u16 Vt[64][68];        // [d][j]   (transposed + key-permuted V)
  __shared__ u16 Ps[4][16][68];     // per-wave P [q][j]
  int t = threadIdx.x;
  int w = t >> 6, l = t & 63;
  int lr = l & 15, lg = l >> 4;
  int bh = blockIdx.y;
  int b = bh / NHEAD, h = bh % NHEAD;
  int q0 = blockIdx.x * 64;
  int sp = blockIdx.z;

  const float QS = 0.1803368801111716f;   // 0.125 * log2(e)
  bf16x8 qf[2];
  {
    const u16* qp = qkv + (size_t)(b * NNCTX + q0 + w * 16 + lr) * 1152 + h * 64;
    #pragma unroll
    for (int c = 0; c < 2; c++){
      U8 r; r.u = *(const uint4*)(qp + c * 32 + lg * 8);
      #pragma unroll
      for (int j = 0; j < 8; j++) r.s[j] = f2bf(bf2f(r.s[j]) * QS);
      qf[c] = r.v;
    }
  }
  bf16x8 onesf;
  {
    U8 r;
    #pragma unroll
    for (int j = 0; j < 8; j++) r.s[j] = 0x3F80;  // bf16 1.0
    onesf = r.v;
  }
  f32x4 oacc[4] = {};
  f32x4 l_acc = {};
  float m_r[4] = { -3.4e38f, -3.4e38f, -3.4e38f, -3.4e38f };

  const size_t kvrow = (size_t)(b * NNCTX) * 1152 + h * 64;
  int key4 = t >> 2, dp4 = (t & 3) * 16;
  int vj = (l & 15) * 4 + (l >> 4);
  int vdp = w * 16;

  uint4 kra, krb, vra, vrb;
  auto LOADT = [&](int kt){
    const u16* kp = qkv + kvrow + (size_t)(kt * 64 + key4) * 1152 + 384 + dp4;
    kra = *(const uint4*)kp;
    krb = *(const uint4*)(kp + 8);
    const u16* vp = qkv + kvrow + (size_t)(kt * 64 + l) * 1152 + 768 + vdp;
    vra = *(const uint4*)vp;
    vrb = *(const uint4*)(vp + 8);
  };
  auto WRITET = [&](){
    *(uint4*)&Ks[key4][dp4]     = kra;
    *(uint4*)&Ks[key4][dp4 + 8] = krb;
    U8 v0, v1; v0.u = vra; v1.u = vrb;
    #pragma unroll
    for (int j = 0; j < 8; j++){ Vt[vdp + j][vj] = v0.s[j]; Vt[vdp + 8 + j][vj] = v1.s[j]; }
  };

  int ktbeg = sp * 16, ktend = ktbeg + 16;
  LOADT(ktbeg);
  WRITET();
  __syncthreads();

  for (int kt = ktbeg; kt < ktend; kt++){
    if (kt + 1 < ktend) LOADT(kt + 1);

    // S = Q K^T (exp2 domain)
    f32x4 s[4] = {};
    #pragma unroll
    for (int ti = 0; ti < 4; ti++){
      #pragma unroll
      for (int c = 0; c < 2; c++){
        bf16x8 kf = *(const bf16x8*)&Ks[ti * 16 + lr][c * 32 + lg * 8];
        s[ti] = __builtin_amdgcn_mfma_f32_16x16x32_bf16(qf[c], kf, s[ti], 0, 0, 0);
      }
    }
    // defer-max: lane-local row maxes, wave-wide skip check (THR = 8 in log2 domain)
    float rml[4];
    #pragma unroll
    for (int r = 0; r < 4; r++)
      rml[r] = fmaxf(fmaxf(s[0][r], s[1][r]), fmaxf(s[2][r], s[3][r]));
    bool ok = (rml[0] <= m_r[0] + 8.f) && (rml[1] <= m_r[1] + 8.f) &&
              (rml[2] <= m_r[2] + 8.f) && (rml[3] <= m_r[3] + 8.f);
    if (!__all(ok)){
      #pragma unroll
      for (int r = 0; r < 4; r++){
        float mt = rml[r];
        mt = fmaxf(mt, __shfl_xor(mt, 1));
        mt = fmaxf(mt, __shfl_xor(mt, 2));
        mt = fmaxf(mt, __shfl_xor(mt, 4));
        mt = fmaxf(mt, __shfl_xor(mt, 8));
        float mn = fmaxf(m_r[r], mt);
        float a = __builtin_exp2f(m_r[r] - mn);
        m_r[r] = mn;
        l_acc[r] *= a;
        #pragma unroll
        for (int dt = 0; dt < 4; dt++) oacc[dt][r] *= a;
      }
    }
    // P = exp2(S - m): packed b64 writes at permuted-contiguous [q][lr*4..+3]
    #pragma unroll
    for (int r = 0; r < 4; r++){
      float p0 = __builtin_exp2f(s[0][r] - m_r[r]);
      float p1 = __builtin_exp2f(s[1][r] - m_r[r]);
      float p2 = __builtin_exp2f(s[2][r] - m_r[r]);
      float p3 = __builtin_exp2f(s[3][r] - m_r[r]);
      uint2 pk;
      pk.x = (u32)f2bf(p0) | ((u32)f2bf(p1) << 16);
      pk.y = (u32)f2bf(p2) | ((u32)f2bf(p3) << 16);
      *(uint2*)&Ps[w][lg * 4 + r][lr * 4] = pk;
    }
    // O += P V ; l += P 1  (same pf, ones B-fragment)
    #pragma unroll
    for (int c = 0; c < 2; c++){
      bf16x8 pf = *(const bf16x8*)&Ps[w][lr][c * 32 + lg * 8];
      l_acc = __builtin_amdgcn_mfma_f32_16x16x32_bf16(pf, onesf, l_acc, 0, 0, 0);
      #pragma unroll
      for (int dt = 0; dt < 4; dt++){
        bf16x8 vf = *(const bf16x8*)&Vt[dt * 16 + lr][c * 32 + lg * 8];
        oacc[dt] = __builtin_amdgcn_mfma_f32_16x16x32_bf16(pf, vf, oacc[dt], 0, 0, 0);
      }
    }
    __syncthreads();                 // all waves done reading K/V
    if (kt + 1 < ktend) WRITET();    // overwrite single buffer
    __syncthreads();                 // staged before next QK
  }
  // epilogue: unnormalized O + (m, l)
  u16* obuf = sp ? o1buf : o0buf;
  #pragma unroll
  for (int r = 0; r < 4; r++){
    int n = q0 + w * 16 + lg * 4 + r;
    size_t row = (size_t)(b * NNCTX + n);
    u16* op = obuf + row * CCH + h * 64 + lr;
    op[0]  = f2bf(oacc[0][r]);
    op[16] = f2bf(oacc[1][r]);
    op[32] = f2bf(oacc[2][r]);
    op[48] = f2bf(oacc[3][r]);
    if (lr == 0)
      mlbuf[((size_t)(sp * BB * NHEAD + bh)) * NNCTX + n] = make_float2(m_r[r], l_acc[r]);
  }
}

// Merge the two KV-splits: O = (O0*2^(m0-M) + O1*2^(m1-M)) / (l0*2^(m0-M) + l1*2^(m1-M))
__global__ __launch_bounds__(128) void attn_combine(const u16* __restrict__ o0, const u16* __restrict__ o1,
    const float2* __restrict__ ml, u16* __restrict__ obuf){
  __shared__ float sc0[NHEAD], sc1[NHEAD];
  int row = blockIdx.x;
  int b = row >> 11, n = row & 2047;
  int t = threadIdx.x;
  if (t < NHEAD){
    float2 a = ml[(size_t)(b * NHEAD + t) * NNCTX + n];
    float2 c = ml[(size_t)(BB * NHEAD + b * NHEAD + t) * NNCTX + n];
    float M = fmaxf(a.x, c.x);
    float e0 = exp2f(a.x - M), e1 = exp2f(c.x - M);
    float inv = 1.0f / (a.y * e0 + c.y * e1);
    sc0[t] = e0 * inv; sc1[t] = e1 * inv;
  }
  __syncthreads();
  size_t base = (size_t)row * CCH;
  #pragma unroll
  for (int i = 0; i < 3; i++){
    int c = t + i * 128;
    int h = c >> 6;
    float v = bf2f(o0[base + c]) * sc0[h] + bf2f(o1[base + c]) * sc1[h];
    obuf[base + c] = f2bf(v);
  }
}

extern "C" void kernel_launch(void* const* d_in, const int* in_sizes, int n_in,
                              void* d_out, int out_size, void* d_ws, size_t ws_size,
                              hipStream_t stream){
  const float* x      = (const float*)d_in[0];
  const float* ln1_g  = (const float*)d_in[1];
  const float* ln1_b  = (const float*)d_in[2];
  const float* w_qkv  = (const float*)d_in[3];
  const float* w_proj = (const float*)d_in[4];
  const float* b_proj = (const float*)d_in[5];
  const float* ln2_g  = (const float*)d_in[6];
  const float* ln2_b  = (const float*)d_in[7];
  const float* w_fc1  = (const float*)d_in[8];
  const float* b_fc1  = (const float*)d_in[9];
  const float* w_fc2  = (const float*)d_in[10];
  const float* b_fc2  = (const float*)d_in[11];
  float* out = (float*)d_out;

  u16* ws = (u16*)d_ws;
  u16* wqkv_bf  = ws;                       // 384*1152 = 442368
  u16* wproj_bf = wqkv_bf + 442368;         // 384*384  = 147456
  u16* wfc1_bf  = wproj_bf + 147456;        // 384*1536 = 589824
  u16* wfc2_bf  = wfc1_bf + 589824;         // 1536*384 = 589824
  u16* h_bf     = wfc2_bf + 589824;         // 8192*384 (LN out; dead after QKV gemm -> reused as opart0; reused as h2 after combine)
  u16* qkv_bf   = h_bf + 3145728;           // 8192*1152
  u16* o_bf     = qkv_bf + 9437184;         // 8192*384 (combined attention out)
  u16* opart1   = o_bf + 3145728;           // 8192*384 (split-1 partial O)
  float2* mlbuf = (float2*)(opart1 + 3145728); // [2][B*H][N] (m,l) = 786 KB
  u16* opart0   = h_bf;
  u16* m_bf     = qkv_bf;                   // 8192*1536 (reuses qkv+o after proj)

  cast_all<<<1728, 256, 0, stream>>>(w_qkv, w_proj, w_fc1, w_fc2, wqkv_bf, wproj_bf, wfc1_bf, wfc2_bf);

  // LN1 -> h (bf16)
  ln_kernel<<<8192, 128, 0, stream>>>(x, ln1_g, ln1_b, h_bf);
  // QKV = h @ w_qkv  [8192,1152] bf16
  gemm_bf16<0, 0><<<dim3(18, 128), 256, 0, stream>>>(h_bf, wqkv_bf, 384, 1152, qkv_bf, nullptr, nullptr, nullptr);
  // attention (KV-split 2) -> partial O + (m,l)
  attn_mfma<<<dim3(32, 24, 2), 256, 0, stream>>>(qkv_bf, opart0, opart1, mlbuf);
  // combine splits -> o (bf16)
  attn_combine<<<8192, 128, 0, stream>>>(opart0, opart1, mlbuf, o_bf);
  // x1 = x + o @ w_proj + b_proj  (fp32, into d_out)
  gemm_bf16<1, 1><<<dim3(6, 128), 256, 0, stream>>>(o_bf, wproj_bf, 384, 384, nullptr, b_proj, x, out);
  // LN2 -> h2 (bf16, reuse h)
  ln_kernel<<<8192, 128, 0, stream>>>(out, ln2_g, ln2_b, h_bf);
  // m = gelu(h2 @ w_fc1 + b_fc1)  bf16
  gemm_bf16<2, 0><<<dim3(24, 128), 256, 0, stream>>>(h_bf, wfc1_bf, 384, 1536, m_bf, b_fc1, nullptr, nullptr);
  // out = x1 + m @ w_fc2 + b_fc2  (fp32, in-place on d_out)
  gemm_bf16<1, 1><<<dim3(6, 128), 256, 0, stream>>>(m_bf, wfc2_bf, 1536, 384, nullptr, b_fc2, out, out);
}

// Round 5
// 243.729 us; speedup vs baseline: 1.0243x; 1.0243x over previous
//
#include <hip/hip_runtime.h>

typedef __bf16 bf16x8 __attribute__((ext_vector_type(8)));
typedef float f32x4 __attribute__((ext_vector_type(4)));
typedef unsigned short u16;
typedef unsigned int u32;

#define BB 4
#define NNCTX 2048
#define CCH 384
#define NHEAD 6
#define DHEAD 64
#define HIDDIM 1536

__device__ __forceinline__ u16 f2bf(float f){
  u32 u = __builtin_bit_cast(u32, f);
  u = u + 0x7fffu + ((u >> 16) & 1u);
  return (u16)(u >> 16);
}
__device__ __forceinline__ float bf2f(u16 h){
  u32 u = ((u32)h) << 16;
  return __builtin_bit_cast(float, u);
}

union U8 { uint4 u; u16 s[8]; bf16x8 v; };

// Merged weight cast: 1769472 elems = 442368 float4 units = 1728 blocks exactly.
__global__ __launch_bounds__(256) void cast_all(const float* __restrict__ w0, const float* __restrict__ w1,
    const float* __restrict__ w2, const float* __restrict__ w3,
    u16* __restrict__ o0, u16* __restrict__ o1, u16* __restrict__ o2, u16* __restrict__ o3){
  int i = blockIdx.x * 256 + threadIdx.x;
  const int n0 = 442368/4, n1 = 147456/4, n2 = 589824/4;
  const float* src; u16* dst; int j;
  if (i < n0){ src = w0; dst = o0; j = i; }
  else if (i < n0 + n1){ src = w1; dst = o1; j = i - n0; }
  else if (i < n0 + n1 + n2){ src = w2; dst = o2; j = i - n0 - n1; }
  else { src = w3; dst = o3; j = i - n0 - n1 - n2; }
  float4 v = ((const float4*)src)[j];
  ushort4 o; o.x = f2bf(v.x); o.y = f2bf(v.y); o.z = f2bf(v.z); o.w = f2bf(v.w);
  ((ushort4*)dst)[j] = o;
}

// One block per row (C=384), 128 threads: each handles 3 elements.
__global__ __launch_bounds__(128) void ln_kernel(const float* __restrict__ x, const float* __restrict__ g,
                                                 const float* __restrict__ bb, u16* __restrict__ out){
  int row = blockIdx.x, t = threadIdx.x;
  const float* xr = x + (size_t)row * CCH;
  float v0 = xr[t], v1 = xr[t + 128], v2 = xr[t + 256];
  float s = v0 + v1 + v2;
  float q = v0 * v0 + v1 * v1 + v2 * v2;
  #pragma unroll
  for (int o = 32; o; o >>= 1){ s += __shfl_down(s, o); q += __shfl_down(q, o); }
  __shared__ float sh[4];
  if ((t & 63) == 0){ int w = t >> 6; sh[w * 2] = s; sh[w * 2 + 1] = q; }
  __syncthreads();
  float sum = sh[0] + sh[2], ssq = sh[1] + sh[3];
  float mu = sum * (1.0f / 384.0f);
  float rstd = rsqrtf(ssq * (1.0f / 384.0f) - mu * mu + 1e-5f);
  size_t base = (size_t)row * CCH;
  out[base + t]       = f2bf((v0 - mu) * rstd * g[t]       + bb[t]);
  out[base + t + 128] = f2bf((v1 - mu) * rstd * g[t + 128] + bb[t + 128]);
  out[base + t + 256] = f2bf((v2 - mu) * rstd * g[t + 256] + bb[t + 256]);
}

// Tiled bf16 MFMA GEMM: C[M,Nn] = A[M,K] @ B[K,Nn]. 64x64 tile, 256 threads (4 waves, 2x2 of 32x32).
// EPI 0: store bf16. EPI 1: fp32 out = resid + acc + bias. EPI 2: bf16 out = gelu(acc + bias).
// DBUF 1: double-buffered LDS + reg prefetch, 1 barrier/iter (for grid-limited launches).
template<int EPI, int DBUF>
__global__ __launch_bounds__(256) void gemm_bf16(const u16* __restrict__ A, const u16* __restrict__ Bm,
    int K, int Nn, u16* __restrict__ outb, const float* __restrict__ bias,
    const float* __restrict__ resid, float* __restrict__ outf)
{
  __shared__ u16 As[DBUF + 1][64][68];
  __shared__ u16 Bs[DBUF + 1][64][68];
  int t = threadIdx.x;
  int bm = blockIdx.y * 64, bn = blockIdx.x * 64;
  int l = t & 63, w = t >> 6;
  int wm = (w >> 1) * 32, wn = (w & 1) * 32;
  f32x4 acc[2][2] = {};
  int ar0 = t >> 3, ac0 = (t & 7) * 8;
  uint4 la0, la1, lb0, lb1;
  auto LOADG = [&](int k0){
    la0 = *(const uint4*)&A[(size_t)(bm + ar0) * K + k0 + ac0];
    la1 = *(const uint4*)&A[(size_t)(bm + ar0 + 32) * K + k0 + ac0];
    lb0 = *(const uint4*)&Bm[(size_t)(k0 + ar0) * Nn + bn + ac0];
    lb1 = *(const uint4*)&Bm[(size_t)(k0 + ar0 + 32) * Nn + bn + ac0];
  };
  auto WRITEL = [&](int bf){
    *(uint4*)&As[bf][ar0][ac0]      = la0;
    *(uint4*)&As[bf][ar0 + 32][ac0] = la1;
    const u16* p0 = (const u16*)&lb0;
    const u16* p1 = (const u16*)&lb1;
    #pragma unroll
    for (int j = 0; j < 8; j++){ Bs[bf][ac0 + j][ar0] = p0[j]; Bs[bf][ac0 + j][ar0 + 32] = p1[j]; }
  };
  auto COMPUTE = [&](int bf){
    #pragma unroll
    for (int ks = 0; ks < 2; ks++){
      int kb = ks * 32 + (l >> 4) * 8;
      bf16x8 a0  = *(const bf16x8*)&As[bf][wm + (l & 15)][kb];
      bf16x8 a1  = *(const bf16x8*)&As[bf][wm + 16 + (l & 15)][kb];
      bf16x8 bb0 = *(const bf16x8*)&Bs[bf][wn + (l & 15)][kb];
      bf16x8 bb1 = *(const bf16x8*)&Bs[bf][wn + 16 + (l & 15)][kb];
      acc[0][0] = __builtin_amdgcn_mfma_f32_16x16x32_bf16(a0, bb0, acc[0][0], 0, 0, 0);
      acc[0][1] = __builtin_amdgcn_mfma_f32_16x16x32_bf16(a0, bb1, acc[0][1], 0, 0, 0);
      acc[1][0] = __builtin_amdgcn_mfma_f32_16x16x32_bf16(a1, bb0, acc[1][0], 0, 0, 0);
      acc[1][1] = __builtin_amdgcn_mfma_f32_16x16x32_bf16(a1, bb1, acc[1][1], 0, 0, 0);
    }
  };
  if constexpr (DBUF){
    int nk = K >> 6;
    LOADG(0);
    WRITEL(0);
    __syncthreads();
    for (int ki = 0; ki < nk; ki++){
      int cur = ki & 1;
      if (ki + 1 < nk) LOADG((ki + 1) << 6);
      COMPUTE(cur);
      if (ki + 1 < nk) WRITEL(cur ^ 1);
      __syncthreads();
    }
  } else {
    for (int k0 = 0; k0 < K; k0 += 64){
      __syncthreads();
      LOADG(k0);
      WRITEL(0);
      __syncthreads();
      COMPUTE(0);
    }
  }
  #pragma unroll
  for (int mi = 0; mi < 2; mi++)
  #pragma unroll
  for (int ni = 0; ni < 2; ni++)
  #pragma unroll
  for (int r = 0; r < 4; r++){
    int row = bm + wm + mi * 16 + ((l >> 4) << 2) + r;
    int col = bn + wn + ni * 16 + (l & 15);
    size_t idx = (size_t)row * Nn + col;
    float v = acc[mi][ni][r];
    if (EPI == 0){
      outb[idx] = f2bf(v);
    } else if (EPI == 1){
      outf[idx] = resid[idx] + v + bias[col];
    } else {
      v += bias[col];
      v = 0.5f * v * (1.0f + erff(v * 0.70710678118f));
      outb[idx] = f2bf(v);
    }
  }
}

// MFMA flash attention, KV-split 2, XCD-pinned block swizzle.
// 1-D grid of 1536; decode keeps all 32 q-blocks of a (b,h,split) group on ONE XCD
// (same id%8 under the dispatch round-robin), so each XCD's L2 holds its 6 groups'
// KV (1.5 MB < 4 MB) and HBM fetch stays ~one pass.
// Single-buffered KV LDS (25.5 KB -> 6 blocks/CU) + register prefetch.
// l via ones-MFMA; defer-max THR=8 (exp2 domain). Outputs unnormalized O + (m,l).
__global__ __launch_bounds__(256, 6) void attn_mfma(const u16* __restrict__ qkv,
    u16* __restrict__ o0buf, u16* __restrict__ o1buf, float2* __restrict__ mlbuf){
  __shared__ u16 Ks[64][68];        // [key][d]
  __shared__ u16 Vt[64][68];        // [d][j]   (transposed + key-permuted V)
  __shared__ u16 Ps[4][16][68];     // per-wave P [q][j]
  int t = threadIdx.x;
  int w = t >> 6, l = t & 63;
  int lr = l & 15, lg = l >> 4;
  // XCD-pinned decode
  int id = blockIdx.x;
  int xcd = id & 7, slot = id >> 3;
  int q0 = (slot & 31) * 64;
  int group = (slot >> 5) * 8 + xcd;       // 0..47
  int bh = group % (BB * NHEAD);
  int sp = group / (BB * NHEAD);
  int b = bh / NHEAD, h = bh % NHEAD;

  const float QS = 0.1803368801111716f;   // 0.125 * log2(e)
  bf16x8 qf[2];
  {
    const u16* qp = qkv + (size_t)(b * NNCTX + q0 + w * 16 + lr) * 1152 + h * 64;
    #pragma unroll
    for (int c = 0; c < 2; c++){
      U8 r; r.u = *(const uint4*)(qp + c * 32 + lg * 8);
      #pragma unroll
      for (int j = 0; j < 8; j++) r.s[j] = f2bf(bf2f(r.s[j]) * QS);
      qf[c] = r.v;
    }
  }
  bf16x8 onesf;
  {
    U8 r;
    #pragma unroll
    for (int j = 0; j < 8; j++) r.s[j] = 0x3F80;  // bf16 1.0
    onesf = r.v;
  }
  f32x4 oacc[4] = {};
  f32x4 l_acc = {};
  float m_r[4] = { -3.4e38f, -3.4e38f, -3.4e38f, -3.4e38f };

  const size_t kvrow = (size_t)(b * NNCTX) * 1152 + h * 64;
  int key4 = t >> 2, dp4 = (t & 3) * 16;
  int vj = (l & 15) * 4 + (l >> 4);
  int vdp = w * 16;

  uint4 kra, krb, vra, vrb;
  auto LOADT = [&](int kt){
    const u16* kp = qkv + kvrow + (size_t)(kt * 64 + key4) * 1152 + 384 + dp4;
    kra = *(const uint4*)kp;
    krb = *(const uint4*)(kp + 8);
    const u16* vp = qkv + kvrow + (size_t)(kt * 64 + l) * 1152 + 768 + vdp;
    vra = *(const uint4*)vp;
    vrb = *(const uint4*)(vp + 8);
  };
  auto WRITET = [&](){
    *(uint4*)&Ks[key4][dp4]     = kra;
    *(uint4*)&Ks[key4][dp4 + 8] = krb;
    U8 v0, v1; v0.u = vra; v1.u = vrb;
    #pragma unroll
    for (int j = 0; j < 8; j++){ Vt[vdp + j][vj] = v0.s[j]; Vt[vdp + 8 + j][vj] = v1.s[j]; }
  };

  int ktbeg = sp * 16, ktend = ktbeg + 16;
  LOADT(ktbeg);
  WRITET();
  __syncthreads();

  for (int kt = ktbeg; kt < ktend; kt++){
    if (kt + 1 < ktend) LOADT(kt + 1);

    // S = Q K^T (exp2 domain)
    f32x4 s[4] = {};
    #pragma unroll
    for (int ti = 0; ti < 4; ti++){
      #pragma unroll
      for (int c = 0; c < 2; c++){
        bf16x8 kf = *(const bf16x8*)&Ks[ti * 16 + lr][c * 32 + lg * 8];
        s[ti] = __builtin_amdgcn_mfma_f32_16x16x32_bf16(qf[c], kf, s[ti], 0, 0, 0);
      }
    }
    // defer-max: lane-local row maxes, wave-wide skip check (THR = 8 in log2 domain)
    float rml[4];
    #pragma unroll
    for (int r = 0; r < 4; r++)
      rml[r] = fmaxf(fmaxf(s[0][r], s[1][r]), fmaxf(s[2][r], s[3][r]));
    bool ok = (rml[0] <= m_r[0] + 8.f) && (rml[1] <= m_r[1] + 8.f) &&
              (rml[2] <= m_r[2] + 8.f) && (rml[3] <= m_r[3] + 8.f);
    if (!__all(ok)){
      #pragma unroll
      for (int r = 0; r < 4; r++){
        float mt = rml[r];
        mt = fmaxf(mt, __shfl_xor(mt, 1));
        mt = fmaxf(mt, __shfl_xor(mt, 2));
        mt = fmaxf(mt, __shfl_xor(mt, 4));
        mt = fmaxf(mt, __shfl_xor(mt, 8));
        float mn = fmaxf(m_r[r], mt);
        float a = __builtin_exp2f(m_r[r] - mn);
        m_r[r] = mn;
        l_acc[r] *= a;
        #pragma unroll
        for (int dt = 0; dt < 4; dt++) oacc[dt][r] *= a;
      }
    }
    // P = exp2(S - m): packed b64 writes at permuted-contiguous [q][lr*4..+3]
    #pragma unroll
    for (int r = 0; r < 4; r++){
      float p0 = __builtin_exp2f(s[0][r] - m_r[r]);
      float p1 = __builtin_exp2f(s[1][r] - m_r[r]);
      float p2 = __builtin_exp2f(s[2][r] - m_r[r]);
      float p3 = __builtin_exp2f(s[3][r] - m_r[r]);
      uint2 pk;
      pk.x = (u32)f2bf(p0) | ((u32)f2bf(p1) << 16);
      pk.y = (u32)f2bf(p2) | ((u32)f2bf(p3) << 16);
      *(uint2*)&Ps[w][lg * 4 + r][lr * 4] = pk;
    }
    // O += P V ; l += P 1  (same pf, ones B-fragment)
    #pragma unroll
    for (int c = 0; c < 2; c++){
      bf16x8 pf = *(const bf16x8*)&Ps[w][lr][c * 32 + lg * 8];
      l_acc = __builtin_amdgcn_mfma_f32_16x16x32_bf16(pf, onesf, l_acc, 0, 0, 0);
      #pragma unroll
      for (int dt = 0; dt < 4; dt++){
        bf16x8 vf = *(const bf16x8*)&Vt[dt * 16 + lr][c * 32 + lg * 8];
        oacc[dt] = __builtin_amdgcn_mfma_f32_16x16x32_bf16(pf, vf, oacc[dt], 0, 0, 0);
      }
    }
    __syncthreads();                 // all waves done reading K/V
    if (kt + 1 < ktend) WRITET();    // overwrite single buffer
    __syncthreads();                 // staged before next QK
  }
  // epilogue: unnormalized O + (m, l)
  u16* obuf = sp ? o1buf : o0buf;
  #pragma unroll
  for (int r = 0; r < 4; r++){
    int n = q0 + w * 16 + lg * 4 + r;
    size_t row = (size_t)(b * NNCTX + n);
    u16* op = obuf + row * CCH + h * 64 + lr;
    op[0]  = f2bf(oacc[0][r]);
    op[16] = f2bf(oacc[1][r]);
    op[32] = f2bf(oacc[2][r]);
    op[48] = f2bf(oacc[3][r]);
    if (lr == 0)
      mlbuf[((size_t)(sp * BB * NHEAD + bh)) * NNCTX + n] = make_float2(m_r[r], l_acc[r]);
  }
}

// Merge the two KV-splits: O = (O0*2^(m0-M) + O1*2^(m1-M)) / (l0*2^(m0-M) + l1*2^(m1-M))
__global__ __launch_bounds__(128) void attn_combine(const u16* __restrict__ o0, const u16* __restrict__ o1,
    const float2* __restrict__ ml, u16* __restrict__ obuf){
  __shared__ float sc0[NHEAD], sc1[NHEAD];
  int row = blockIdx.x;
  int b = row >> 11, n = row & 2047;
  int t = threadIdx.x;
  if (t < NHEAD){
    float2 a = ml[(size_t)(b * NHEAD + t) * NNCTX + n];
    float2 c = ml[(size_t)(BB * NHEAD + b * NHEAD + t) * NNCTX + n];
    float M = fmaxf(a.x, c.x);
    float e0 = exp2f(a.x - M), e1 = exp2f(c.x - M);
    float inv = 1.0f / (a.y * e0 + c.y * e1);
    sc0[t] = e0 * inv; sc1[t] = e1 * inv;
  }
  __syncthreads();
  size_t base = (size_t)row * CCH;
  #pragma unroll
  for (int i = 0; i < 3; i++){
    int c = t + i * 128;
    int h = c >> 6;
    float v = bf2f(o0[base + c]) * sc0[h] + bf2f(o1[base + c]) * sc1[h];
    obuf[base + c] = f2bf(v);
  }
}

extern "C" void kernel_launch(void* const* d_in, const int* in_sizes, int n_in,
                              void* d_out, int out_size, void* d_ws, size_t ws_size,
                              hipStream_t stream){
  const float* x      = (const float*)d_in[0];
  const float* ln1_g  = (const float*)d_in[1];
  const float* ln1_b  = (const float*)d_in[2];
  const float* w_qkv  = (const float*)d_in[3];
  const float* w_proj = (const float*)d_in[4];
  const float* b_proj = (const float*)d_in[5];
  const float* ln2_g  = (const float*)d_in[6];
  const float* ln2_b  = (const float*)d_in[7];
  const float* w_fc1  = (const float*)d_in[8];
  const float* b_fc1  = (const float*)d_in[9];
  const float* w_fc2  = (const float*)d_in[10];
  const float* b_fc2  = (const float*)d_in[11];
  float* out = (float*)d_out;

  u16* ws = (u16*)d_ws;
  u16* wqkv_bf  = ws;                       // 384*1152 = 442368
  u16* wproj_bf = wqkv_bf + 442368;         // 384*384  = 147456
  u16* wfc1_bf  = wproj_bf + 147456;        // 384*1536 = 589824
  u16* wfc2_bf  = wfc1_bf + 589824;         // 1536*384 = 589824
  u16* h_bf     = wfc2_bf + 589824;         // 8192*384 (LN out; dead after QKV gemm -> reused as opart0; reused as h2 after combine)
  u16* qkv_bf   = h_bf + 3145728;           // 8192*1152
  u16* o_bf     = qkv_bf + 9437184;         // 8192*384 (combined attention out)
  u16* opart1   = o_bf + 3145728;           // 8192*384 (split-1 partial O)
  float2* mlbuf = (float2*)(opart1 + 3145728); // [2][B*H][N] (m,l) = 786 KB
  u16* opart0   = h_bf;
  u16* m_bf     = qkv_bf;                   // 8192*1536 (reuses qkv+o after proj)

  cast_all<<<1728, 256, 0, stream>>>(w_qkv, w_proj, w_fc1, w_fc2, wqkv_bf, wproj_bf, wfc1_bf, wfc2_bf);

  // LN1 -> h (bf16)
  ln_kernel<<<8192, 128, 0, stream>>>(x, ln1_g, ln1_b, h_bf);
  // QKV = h @ w_qkv  [8192,1152] bf16
  gemm_bf16<0, 0><<<dim3(18, 128), 256, 0, stream>>>(h_bf, wqkv_bf, 384, 1152, qkv_bf, nullptr, nullptr, nullptr);
  // attention (KV-split 2, XCD-pinned) -> partial O + (m,l)
  attn_mfma<<<dim3(1536), 256, 0, stream>>>(qkv_bf, opart0, opart1, mlbuf);
  // combine splits -> o (bf16)
  attn_combine<<<8192, 128, 0, stream>>>(opart0, opart1, mlbuf, o_bf);
  // x1 = x + o @ w_proj + b_proj  (fp32, into d_out)
  gemm_bf16<1, 1><<<dim3(6, 128), 256, 0, stream>>>(o_bf, wproj_bf, 384, 384, nullptr, b_proj, x, out);
  // LN2 -> h2 (bf16, reuse h)
  ln_kernel<<<8192, 128, 0, stream>>>(out, ln2_g, ln2_b, h_bf);
  // m = gelu(h2 @ w_fc1 + b_fc1)  bf16
  gemm_bf16<2, 0><<<dim3(24, 128), 256, 0, stream>>>(h_bf, wfc1_bf, 384, 1536, m_bf, b_fc1, nullptr, nullptr);
  // out = x1 + m @ w_fc2 + b_fc2  (fp32, in-place on d_out)
  gemm_bf16<1, 1><<<dim3(6, 128), 256, 0, stream>>>(m_bf, wfc2_bf, 1536, 384, nullptr, b_fc2, out, out);
}

// Round 6
// 172.165 us; speedup vs baseline: 1.4500x; 1.4157x over previous
//
#include <hip/hip_runtime.h>

typedef __bf16 bf16x8 __attribute__((ext_vector_type(8)));
typedef float f32x4 __attribute__((ext_vector_type(4)));
typedef float f32x16 __attribute__((ext_vector_type(16)));
typedef unsigned short u16;
typedef unsigned int u32;
typedef unsigned long long u64;

#define BB 4
#define NNCTX 2048
#define CCH 384
#define NHEAD 6
#define DHEAD 64
#define HIDDIM 1536

__device__ __forceinline__ u16 f2bf(float f){
  u32 u = __builtin_bit_cast(u32, f);
  u = u + 0x7fffu + ((u >> 16) & 1u);
  return (u16)(u >> 16);
}
__device__ __forceinline__ float bf2f(u16 h){
  u32 u = ((u32)h) << 16;
  return __builtin_bit_cast(float, u);
}

union U8 { uint4 u; u16 s[8]; bf16x8 v; };
union F8 { u32 w[4]; bf16x8 v; };

// Cast + TRANSPOSE all 4 weights to bf16 [N][K] (k-contiguous) via LDS-tiled 64x64 transpose.
// Tile counts: qkv 6*18=108, proj 36, fc1 144, fc2 144 -> 432 blocks.
__global__ __launch_bounds__(256) void cast_tr(const float* __restrict__ w0, const float* __restrict__ w1,
    const float* __restrict__ w2, const float* __restrict__ w3,
    u16* __restrict__ o0, u16* __restrict__ o1, u16* __restrict__ o2, u16* __restrict__ o3){
  __shared__ float S[64][65];
  int idx = blockIdx.x;
  const float* src; u16* dst; int K, N, kt, nt;
  if (idx < 108){ src = w0; dst = o0; K = 384; N = 1152; kt = idx / 18; nt = idx % 18; }
  else if (idx < 144){ idx -= 108; src = w1; dst = o1; K = 384; N = 384; kt = idx / 6; nt = idx % 6; }
  else if (idx < 288){ idx -= 144; src = w2; dst = o2; K = 384; N = 1536; kt = idx / 24; nt = idx % 24; }
  else { idx -= 288; src = w3; dst = o3; K = 1536; N = 384; kt = idx / 6; nt = idx % 6; }
  int t = threadIdx.x;
  int r4 = t >> 6, c = t & 63;
  int k0 = kt * 64, n0 = nt * 64;
  #pragma unroll
  for (int i = 0; i < 16; i++){
    int row = i * 4 + r4;
    S[row][c] = src[(size_t)(k0 + row) * N + n0 + c];
  }
  __syncthreads();
  #pragma unroll
  for (int i = 0; i < 16; i++){
    int row = i * 4 + r4;    // n-index
    dst[(size_t)(n0 + row) * K + k0 + c] = f2bf(S[c][row]);
  }
}

// One block per row (C=384), 128 threads.
__global__ __launch_bounds__(128) void ln_kernel(const float* __restrict__ x, const float* __restrict__ g,
                                                 const float* __restrict__ bb, u16* __restrict__ out){
  int row = blockIdx.x, t = threadIdx.x;
  const float* xr = x + (size_t)row * CCH;
  float v0 = xr[t], v1 = xr[t + 128], v2 = xr[t + 256];
  float s = v0 + v1 + v2;
  float q = v0 * v0 + v1 * v1 + v2 * v2;
  #pragma unroll
  for (int o = 32; o; o >>= 1){ s += __shfl_down(s, o); q += __shfl_down(q, o); }
  __shared__ float sh[4];
  if ((t & 63) == 0){ int w = t >> 6; sh[w * 2] = s; sh[w * 2 + 1] = q; }
  __syncthreads();
  float sum = sh[0] + sh[2], ssq = sh[1] + sh[3];
  float mu = sum * (1.0f / 384.0f);
  float rstd = rsqrtf(ssq * (1.0f / 384.0f) - mu * mu + 1e-5f);
  size_t base = (size_t)row * CCH;
  out[base + t]       = f2bf((v0 - mu) * rstd * g[t]       + bb[t]);
  out[base + t + 128] = f2bf((v1 - mu) * rstd * g[t + 128] + bb[t + 128]);
  out[base + t + 256] = f2bf((v2 - mu) * rstd * g[t + 256] + bb[t + 256]);
}

// Tiled bf16 MFMA GEMM: C[M,Nn] = A[M,K] @ B^T where Bt is [Nn][K] k-contiguous (pre-transposed).
// 64x64 tile, 256 threads (4 waves, 2x2 of 32x32 out). Both staging paths are vector b128 writes.
template<int EPI, int DBUF>
__global__ __launch_bounds__(256) void gemm_bf16(const u16* __restrict__ A, const u16* __restrict__ Bt,
    int K, int Nn, u16* __restrict__ outb, const float* __restrict__ bias,
    const float* __restrict__ resid, float* __restrict__ outf)
{
  __shared__ u16 As[DBUF + 1][64][68];
  __shared__ u16 Bs[DBUF + 1][64][68];
  int t = threadIdx.x;
  int bm = blockIdx.y * 64, bn = blockIdx.x * 64;
  int l = t & 63, w = t >> 6;
  int wm = (w >> 1) * 32, wn = (w & 1) * 32;
  f32x4 acc[2][2] = {};
  int ar0 = t >> 3, ac0 = (t & 7) * 8;
  uint4 la0, la1, lb0, lb1;
  auto LOADG = [&](int k0){
    la0 = *(const uint4*)&A[(size_t)(bm + ar0) * K + k0 + ac0];
    la1 = *(const uint4*)&A[(size_t)(bm + ar0 + 32) * K + k0 + ac0];
    lb0 = *(const uint4*)&Bt[(size_t)(bn + ar0) * K + k0 + ac0];
    lb1 = *(const uint4*)&Bt[(size_t)(bn + ar0 + 32) * K + k0 + ac0];
  };
  auto WRITEL = [&](int bf){
    *(uint4*)&As[bf][ar0][ac0]      = la0;
    *(uint4*)&As[bf][ar0 + 32][ac0] = la1;
    *(uint4*)&Bs[bf][ar0][ac0]      = lb0;
    *(uint4*)&Bs[bf][ar0 + 32][ac0] = lb1;
  };
  auto COMPUTE = [&](int bf){
    #pragma unroll
    for (int ks = 0; ks < 2; ks++){
      int kb = ks * 32 + (l >> 4) * 8;
      bf16x8 a0  = *(const bf16x8*)&As[bf][wm + (l & 15)][kb];
      bf16x8 a1  = *(const bf16x8*)&As[bf][wm + 16 + (l & 15)][kb];
      bf16x8 bb0 = *(const bf16x8*)&Bs[bf][wn + (l & 15)][kb];
      bf16x8 bb1 = *(const bf16x8*)&Bs[bf][wn + 16 + (l & 15)][kb];
      acc[0][0] = __builtin_amdgcn_mfma_f32_16x16x32_bf16(a0, bb0, acc[0][0], 0, 0, 0);
      acc[0][1] = __builtin_amdgcn_mfma_f32_16x16x32_bf16(a0, bb1, acc[0][1], 0, 0, 0);
      acc[1][0] = __builtin_amdgcn_mfma_f32_16x16x32_bf16(a1, bb0, acc[1][0], 0, 0, 0);
      acc[1][1] = __builtin_amdgcn_mfma_f32_16x16x32_bf16(a1, bb1, acc[1][1], 0, 0, 0);
    }
  };
  if constexpr (DBUF){
    int nk = K >> 6;
    LOADG(0);
    WRITEL(0);
    __syncthreads();
    for (int ki = 0; ki < nk; ki++){
      int cur = ki & 1;
      if (ki + 1 < nk) LOADG((ki + 1) << 6);
      COMPUTE(cur);
      if (ki + 1 < nk) WRITEL(cur ^ 1);
      __syncthreads();
    }
  } else {
    for (int k0 = 0; k0 < K; k0 += 64){
      __syncthreads();
      LOADG(k0);
      WRITEL(0);
      __syncthreads();
      COMPUTE(0);
    }
  }
  #pragma unroll
  for (int mi = 0; mi < 2; mi++)
  #pragma unroll
  for (int ni = 0; ni < 2; ni++)
  #pragma unroll
  for (int r = 0; r < 4; r++){
    int row = bm + wm + mi * 16 + ((l >> 4) << 2) + r;
    int col = bn + wn + ni * 16 + (l & 15);
    size_t idx = (size_t)row * Nn + col;
    float v = acc[mi][ni][r];
    if (EPI == 0){
      outb[idx] = f2bf(v);
    } else if (EPI == 1){
      outf[idx] = resid[idx] + v + bias[col];
    } else {
      v += bias[col];
      v = 0.5f * v * (1.0f + erff(v * 0.70710678118f));
      outb[idx] = f2bf(v);
    }
  }
}

// 4 tr_b64 reads (V B-frags for both 32-wide d-tiles at one k-step) + waitcnt, then 3 MFMA.
// Offsets are compile-time literals: C2*2048 + {0,512} (nt0 subtile pair), {256,768} (nt1).
#define PVSTEP(C2, O0, O1, O2, O3)                                               \
  {                                                                              \
    bf16x8 pf = *(const bf16x8*)&Ps[w][l & 31][(C2) * 16 + hi8];                 \
    u64 ta, tb, tc, td;                                                          \
    asm volatile("ds_read_b64_tr_b16 %0, %4 offset:" #O0 "\n\t"                  \
                 "ds_read_b64_tr_b16 %1, %4 offset:" #O1 "\n\t"                  \
                 "ds_read_b64_tr_b16 %2, %4 offset:" #O2 "\n\t"                  \
                 "ds_read_b64_tr_b16 %3, %4 offset:" #O3 "\n\t"                  \
                 "s_waitcnt lgkmcnt(0)"                                          \
                 : "=&v"(ta), "=&v"(tb), "=&v"(tc), "=&v"(td)                    \
                 : "v"(vtr));                                                    \
    __builtin_amdgcn_sched_barrier(0);                                           \
    F8 f0, f1;                                                                   \
    f0.w[0] = (u32)ta; f0.w[1] = (u32)(ta >> 32);                                \
    f0.w[2] = (u32)tb; f0.w[3] = (u32)(tb >> 32);                                \
    f1.w[0] = (u32)tc; f1.w[1] = (u32)(tc >> 32);                                \
    f1.w[2] = (u32)td; f1.w[3] = (u32)(td >> 32);                                \
    l_acc = __builtin_amdgcn_mfma_f32_32x32x16_bf16(pf, onesf, l_acc, 0, 0, 0);  \
    o_0 = __builtin_amdgcn_mfma_f32_32x32x16_bf16(pf, f0.v, o_0, 0, 0, 0);       \
    o_1 = __builtin_amdgcn_mfma_f32_32x32x16_bf16(pf, f1.v, o_1, 0, 0, 0);       \
  }

// MFMA flash attention, 32x32 fragments. Block = 256 thr (4 waves), q-tile 128 (32 q/wave),
// KV tile 64, KV-split 2, XCD-pinned. V in tr-subtiled LDS ([j4][dt][4][16], key-permuted
// j=(key&31)*2+(key>>5)); PV B-frags via ds_read_b64_tr_b16. l via ones-MFMA; defer-max THR=8.
__global__ __launch_bounds__(256, 3) void attn_mfma(const u16* __restrict__ qkv,
    u16* __restrict__ o0buf, u16* __restrict__ o1buf, float2* __restrict__ mlbuf){
  __shared__ u16 Ks[64][68];                         // [key][d]
  __shared__ __attribute__((aligned(128))) u16 Vs[4096];  // [j4][dt][4][16] subtiled
  __shared__ u16 Ps[4][32][72];                      // per-wave P [q][j]
  int t = threadIdx.x;
  int w = t >> 6, l = t & 63;
  int c31 = l & 31, hi = l >> 5, hi8 = hi * 8;
  // XCD-pinned decode: 768 blocks = 48 groups x 16 q-blocks; group pinned to id&7.
  int id = blockIdx.x;
  int xcd = id & 7, slot = id >> 3;
  int qb = slot & 15;
  int group = (slot >> 4) * 8 + xcd;                 // 0..47
  int bh = group % (BB * NHEAD);
  int sp = group / (BB * NHEAD);
  int b = bh / NHEAD, h = bh % NHEAD;
  int q0 = qb * 128;

  const float QS = 0.1803368801111716f;              // 0.125 * log2(e)
  // Q A-frags (32x32): A[row=c31][k=hi8+j], k-step c: d = c*16 + hi8 + j
  bf16x8 qf[4];
  {
    const u16* qp = qkv + (size_t)(b * NNCTX + q0 + w * 32 + c31) * 1152 + h * 64 + hi8;
    #pragma unroll
    for (int c = 0; c < 4; c++){
      U8 r; r.u = *(const uint4*)(qp + c * 16);
      #pragma unroll
      for (int j = 0; j < 8; j++) r.s[j] = f2bf(bf2f(r.s[j]) * QS);
      qf[c] = r.v;
    }
  }
  bf16x8 onesf;
  {
    U8 r;
    #pragma unroll
    for (int j = 0; j < 8; j++) r.s[j] = 0x3F80;
    onesf = r.v;
  }
  f32x16 o_0 = {}, o_1 = {};                          // d-cols c31, 32+c31
  f32x16 l_acc = {};
  float m_r[16];
  #pragma unroll
  for (int r = 0; r < 16; r++) m_r[r] = -3.4e38f;

  const size_t kvrow = (size_t)(b * NNCTX) * 1152 + h * 64;
  int kkey = t >> 2, kdp = (t & 3) * 16;             // K staging
  int vkey = t & 63, vdblk = (t >> 6) * 16;          // V staging
  int vj = ((vkey & 31) << 1) | (vkey >> 5);
  int voff = (vj >> 2) * 256 + (vdblk >> 4) * 64 + (vj & 3) * 16;   // u16 units
  // tr-read base: group lg -> subtile (lg>>1)*2 (k-half) at dt (lg&1); column lr.
  int lg = l >> 4, lr = l & 15;
  u32 vtr = (u32)(uintptr_t)(&Vs[0]) + (u32)((lg >> 1) * 1024 + (lg & 1) * 128 + lr * 8);

  uint4 kra, krb, vra, vrb;
  auto LOADT = [&](int kt){
    const u16* kp = qkv + kvrow + (size_t)(kt * 64 + kkey) * 1152 + 384 + kdp;
    kra = *(const uint4*)kp;
    krb = *(const uint4*)(kp + 8);
    const u16* vp = qkv + kvrow + (size_t)(kt * 64 + vkey) * 1152 + 768 + vdblk;
    vra = *(const uint4*)vp;
    vrb = *(const uint4*)(vp + 8);
  };
  auto WRITET = [&](){
    *(uint4*)&Ks[kkey][kdp]     = kra;
    *(uint4*)&Ks[kkey][kdp + 8] = krb;
    *(uint4*)&Vs[voff]     = vra;
    *(uint4*)&Vs[voff + 8] = vrb;
  };

  int ktbeg = sp * 16, ktend = ktbeg + 16;
  LOADT(ktbeg);
  WRITET();
  __syncthreads();

  for (int kt = ktbeg; kt < ktend; kt++){
    if (kt + 1 < ktend) LOADT(kt + 1);

    // S = Q K^T (exp2 domain): key-tiles 0/1 -> cols c31 / 32+c31
    f32x16 s0 = {}, s1 = {};
    #pragma unroll
    for (int c = 0; c < 4; c++){
      bf16x8 kf0 = *(const bf16x8*)&Ks[c31][c * 16 + hi8];
      bf16x8 kf1 = *(const bf16x8*)&Ks[32 + c31][c * 16 + hi8];
      s0 = __builtin_amdgcn_mfma_f32_32x32x16_bf16(qf[c], kf0, s0, 0, 0, 0);
      s1 = __builtin_amdgcn_mfma_f32_32x32x16_bf16(qf[c], kf1, s1, 0, 0, 0);
    }
    // defer-max (THR=8, lane-local check)
    bool ok = true;
    float rml[16];
    #pragma unroll
    for (int r = 0; r < 16; r++){
      rml[r] = fmaxf(s0[r], s1[r]);
      ok = ok && (rml[r] <= m_r[r] + 8.f);
    }
    if (!__all(ok)){
      #pragma unroll
      for (int r = 0; r < 16; r++){
        float mt = rml[r];
        mt = fmaxf(mt, __shfl_xor(mt, 1));
        mt = fmaxf(mt, __shfl_xor(mt, 2));
        mt = fmaxf(mt, __shfl_xor(mt, 4));
        mt = fmaxf(mt, __shfl_xor(mt, 8));
        mt = fmaxf(mt, __shfl_xor(mt, 16));
        float mn = fmaxf(m_r[r], mt);
        float a = __builtin_exp2f(m_r[r] - mn);
        m_r[r] = mn;
        l_acc[r] *= a;
        o_0[r] *= a;
        o_1[r] *= a;
      }
    }
    // P = exp2(S - m): one packed b32 per C-row (keys c31 and 32+c31 -> j = c31*2, +1)
    #pragma unroll
    for (int r = 0; r < 16; r++){
      float p0 = __builtin_exp2f(s0[r] - m_r[r]);
      float p1 = __builtin_exp2f(s1[r] - m_r[r]);
      int crow = (r & 3) + 8 * (r >> 2) + 4 * hi;
      *(u32*)&Ps[w][crow][c31 * 2] = (u32)f2bf(p0) | ((u32)f2bf(p1) << 16);
    }
    // O += P V ; l += P 1  (4 k-steps over permuted j)
    PVSTEP(0, 0, 512, 256, 768)
    PVSTEP(1, 2048, 2560, 2304, 2816)
    PVSTEP(2, 4096, 4608, 4352, 4864)
    PVSTEP(3, 6144, 6656, 6400, 6912)

    __syncthreads();
    if (kt + 1 < ktend) WRITET();
    __syncthreads();
  }
  // epilogue: unnormalized O + (m, l)
  u16* obuf = sp ? o1buf : o0buf;
  #pragma unroll
  for (int r = 0; r < 16; r++){
    int n = q0 + w * 32 + (r & 3) + 8 * (r >> 2) + 4 * hi;
    size_t row = (size_t)(b * NNCTX + n);
    u16* op = obuf + row * CCH + h * 64;
    op[c31]      = f2bf(o_0[r]);
    op[32 + c31] = f2bf(o_1[r]);
    if (c31 == 0)
      mlbuf[((size_t)(sp * BB * NHEAD + bh)) * NNCTX + n] = make_float2(m_r[r], l_acc[r]);
  }
}

// Merge the two KV-splits.
__global__ __launch_bounds__(128) void attn_combine(const u16* __restrict__ o0, const u16* __restrict__ o1,
    const float2* __restrict__ ml, u16* __restrict__ obuf){
  __shared__ float sc0[NHEAD], sc1[NHEAD];
  int row = blockIdx.x;
  int b = row >> 11, n = row & 2047;
  int t = threadIdx.x;
  if (t < NHEAD){
    float2 a = ml[(size_t)(b * NHEAD + t) * NNCTX + n];
    float2 c = ml[(size_t)(BB * NHEAD + b * NHEAD + t) * NNCTX + n];
    float M = fmaxf(a.x, c.x);
    float e0 = exp2f(a.x - M), e1 = exp2f(c.x - M);
    float inv = 1.0f / (a.y * e0 + c.y * e1);
    sc0[t] = e0 * inv; sc1[t] = e1 * inv;
  }
  __syncthreads();
  size_t base = (size_t)row * CCH;
  #pragma unroll
  for (int i = 0; i < 3; i++){
    int c = t + i * 128;
    int h = c >> 6;
    float v = bf2f(o0[base + c]) * sc0[h] + bf2f(o1[base + c]) * sc1[h];
    obuf[base + c] = f2bf(v);
  }
}

extern "C" void kernel_launch(void* const* d_in, const int* in_sizes, int n_in,
                              void* d_out, int out_size, void* d_ws, size_t ws_size,
                              hipStream_t stream){
  const float* x      = (const float*)d_in[0];
  const float* ln1_g  = (const float*)d_in[1];
  const float* ln1_b  = (const float*)d_in[2];
  const float* w_qkv  = (const float*)d_in[3];
  const float* w_proj = (const float*)d_in[4];
  const float* b_proj = (const float*)d_in[5];
  const float* ln2_g  = (const float*)d_in[6];
  const float* ln2_b  = (const float*)d_in[7];
  const float* w_fc1  = (const float*)d_in[8];
  const float* b_fc1  = (const float*)d_in[9];
  const float* w_fc2  = (const float*)d_in[10];
  const float* b_fc2  = (const float*)d_in[11];
  float* out = (float*)d_out;

  u16* ws = (u16*)d_ws;
  u16* wqkv_bf  = ws;                       // [1152][384] transposed
  u16* wproj_bf = wqkv_bf + 442368;         // [384][384]
  u16* wfc1_bf  = wproj_bf + 147456;        // [1536][384]
  u16* wfc2_bf  = wfc1_bf + 589824;         // [384][1536]
  u16* h_bf     = wfc2_bf + 589824;         // 8192*384 (LN out; reused as opart0, then h2)
  u16* qkv_bf   = h_bf + 3145728;           // 8192*1152
  u16* o_bf     = qkv_bf + 9437184;         // 8192*384 (combined attention out)
  u16* opart1   = o_bf + 3145728;           // 8192*384
  float2* mlbuf = (float2*)(opart1 + 3145728); // [2][B*H][N]
  u16* opart0   = h_bf;
  u16* m_bf     = qkv_bf;                   // 8192*1536 (reuses qkv+o after proj)

  cast_tr<<<432, 256, 0, stream>>>(w_qkv, w_proj, w_fc1, w_fc2, wqkv_bf, wproj_bf, wfc1_bf, wfc2_bf);

  // LN1 -> h (bf16)
  ln_kernel<<<8192, 128, 0, stream>>>(x, ln1_g, ln1_b, h_bf);
  // QKV = h @ w_qkv
  gemm_bf16<0, 0><<<dim3(18, 128), 256, 0, stream>>>(h_bf, wqkv_bf, 384, 1152, qkv_bf, nullptr, nullptr, nullptr);
  // attention (KV-split 2, XCD-pinned, 32x32 MFMA) -> partial O + (m,l)
  attn_mfma<<<dim3(768), 256, 0, stream>>>(qkv_bf, opart0, opart1, mlbuf);
  // combine splits -> o (bf16)
  attn_combine<<<8192, 128, 0, stream>>>(opart0, opart1, mlbuf, o_bf);
  // x1 = x + o @ w_proj + b_proj
  gemm_bf16<1, 1><<<dim3(6, 128), 256, 0, stream>>>(o_bf, wproj_bf, 384, 384, nullptr, b_proj, x, out);
  // LN2 -> h2
  ln_kernel<<<8192, 128, 0, stream>>>(out, ln2_g, ln2_b, h_bf);
  // m = gelu(h2 @ w_fc1 + b_fc1)
  gemm_bf16<2, 0><<<dim3(24, 128), 256, 0, stream>>>(h_bf, wfc1_bf, 384, 1536, m_bf, b_fc1, nullptr, nullptr);
  // out = x1 + m @ w_fc2 + b_fc2
  gemm_bf16<1, 1><<<dim3(6, 128), 256, 0, stream>>>(m_bf, wfc2_bf, 1536, 384, nullptr, b_fc2, out, out);
}